// Round 5
// baseline (127.904 us; speedup 1.0000x reference)
//
#include <hip/hip_runtime.h>
#include <math.h>

// Problem constants (from reference setup_inputs)
#define BS 64      // batch
#define F  256     // features (K of the Gram matmul)
#define M  128     // columns  (M=N of the Gram matmul)
#define MF (M * F) // u16 elements per matrix in hT (32768)
#define NTILE 528  // 2x2 row-pair tiles over upper triangle: 32*33/2

typedef unsigned short u16;
typedef _Float16 f16x8 __attribute__((ext_vector_type(8)));
typedef float    f32x16 __attribute__((ext_vector_type(16)));

// ---------------------------------------------------------------------------
// Pre-pass: fp32 [f][m] -> fp16 GRANULE-MAJOR hT[b][f8][m][8]. (round 6:
// coalesced staging worth 107->58 us; layout verified.)
// ---------------------------------------------------------------------------
__global__ __launch_bounds__(256) void convert_f16_kernel(
    const float* __restrict__ m1, const float* __restrict__ m2,
    u16* __restrict__ hT)
{
    __shared__ float tile[64 * M];   // 32 KB
    const int mat = blockIdx.x >> 6;
    const int b   = blockIdx.x & 63;
    const int f0  = blockIdx.y * 64;
    const float* src = (mat == 0 ? m1 : m2) + (size_t)b * MF + (size_t)f0 * M;
    const int tid = threadIdx.x;

    const float4* g = (const float4*)src;
    float4* s = (float4*)tile;
    #pragma unroll
    for (int i = 0; i < 8; ++i)
        s[tid + i * 256] = g[tid + i * 256];
    __syncthreads();

    const size_t obase = ((size_t)(mat * BS + b) * 32 + (f0 >> 3)) * 1024;
    #pragma unroll
    for (int it = 0; it < 4; ++it) {
        const int idx = it * 256 + tid;
        const int f8l = idx >> 7;
        const int m   = idx & 127;
        u16 hh[8] __attribute__((aligned(16)));
        #pragma unroll
        for (int j = 0; j < 8; ++j) {
            const float x = tile[(f8l * 8 + j) * M + m];  // 2 lanes/bank: free
            const _Float16 h = (_Float16)x;               // RNE
            hh[j] = __builtin_bit_cast(u16, h);
        }
        *(uint4*)&hT[obase + (size_t)idx * 8] = *(const uint4*)hh;
    }
}

// ---------------------------------------------------------------------------
// ROUND 13. Re-derived bottleneck from r9-r12 data: per-period wall time
// scales with per-period GLOBAL BYTES (r1 6KB/wave->3.3k cyc; r12 12KB->6.6k)
// at a constant ~15 B/cyc/CU return throughput -- the kernel is bound by the
// global re-read volume (405 MB) through a miss-dominated L2 (hT=8.4MB >
// 4MB/XCD; round-robin dispatch randomizes rows per XCD; L3 serves ~370MB).
// Schedule experiments (barrier count, prefetch depth, occupancy) were all
// neutral -- consistent with this model, and all are abandoned.
// FIX 1 (bytes): 2x2 super-tile. One block = rows (a1,a2)x(b1,b2) = 4 Gram
// matrices from 4 staged rows: 64 KB fetched/matrix vs 96 -> 405->270 MB.
// 8 waves; wave w -> matrix m=w>>1 (ai=m>>1, bj=m&1), col-half c=w&1; each
// wave = half-matrix 128x64, acc=128 AGPR (r1's verified per-wave shape).
// 4 rows staged in K=64 slices (one slice = contiguous 16KB chunk of hT,
// fragment layout IDENTICAL to verified r12), double-buffered = 128 KB LDS.
// FIX 2 (locality): XCD-bijective swizzle (528=8*66): each XCD gets a
// contiguous tile band -> A rows (~0.6MB) L2-resident, B rows clustered.
// Diagonal tiles compute (a1,a2)&(a2,a1) transpose-twins: min/max/hist are
// permutation-invariant -> byte-identical writes, benign.
// ---------------------------------------------------------------------------

#define SLOAD(S) {                                    \
    const u16* sp = srcp + (S) * 8192;                \
    sr0 = *(const uint4*)(sp);                        \
    sr1 = *(const uint4*)(sp + 1024);                 \
    sr2 = *(const uint4*)(sp + 2048);                 \
    sr3 = *(const uint4*)(sp + 3072);                 \
    sr4 = *(const uint4*)(sp + 4096);                 \
    sr5 = *(const uint4*)(sp + 5120);                 \
    sr6 = *(const uint4*)(sp + 6144);                 \
    sr7 = *(const uint4*)(sp + 7168);                 \
}

#define SWRITE(BUF) {                                 \
    u16* dp = &lds[dstb + (BUF)];                     \
    *(uint4*)(dp)        = sr0;                       \
    *(uint4*)(dp + 1024) = sr1;                       \
    *(uint4*)(dp + 2048) = sr2;                       \
    *(uint4*)(dp + 3072) = sr3;                       \
    *(uint4*)(dp + 4096) = sr4;                       \
    *(uint4*)(dp + 5120) = sr5;                       \
    *(uint4*)(dp + 6144) = sr6;                       \
    *(uint4*)(dp + 7168) = sr7;                       \
}

// One K=64 slice: 4 K-steps (ITl x kk); per step: 4 A-frags + 2 B-frags
// from LDS, 8 MFMAs. 24 ds_read_b128 + 32 MFMA per wave per slice.
#define MFMA_SLICE(BUF) {                                                                             \
    __builtin_amdgcn_s_setprio(1);                                                                    \
    _Pragma("unroll")                                                                                 \
    for (int ITl = 0; ITl < 2; ++ITl) {                                                               \
        _Pragma("unroll")                                                                             \
        for (int kk = 0; kk < 2; ++kk) {                                                              \
            const int base = (BUF) + ITl * 4096 + kk * 2048;                                          \
            f16x8 af[4], bf[2];                                                                       \
            _Pragma("unroll")                                                                         \
            for (int t = 0; t < 4; ++t)                                                               \
                af[t] = *(const f16x8*)&lds[base + aoffW + t * 256];                                  \
            bf[0] = *(const f16x8*)&lds[base + boffW];                                                \
            bf[1] = *(const f16x8*)&lds[base + boffW + 256];                                          \
            _Pragma("unroll")                                                                         \
            for (int ti = 0; ti < 4; ++ti) {                                                          \
                acc[ti][0] = __builtin_amdgcn_mfma_f32_32x32x16_f16(af[ti], bf[0], acc[ti][0], 0, 0, 0); \
                acc[ti][1] = __builtin_amdgcn_mfma_f32_32x32x16_f16(af[ti], bf[1], acc[ti][1], 0, 0, 0); \
            }                                                                                         \
        }                                                                                             \
    }                                                                                                 \
    __builtin_amdgcn_s_setprio(0);                                                                    \
}

__global__ __launch_bounds__(512, 2) void gram_hist_mfma(
    const u16* __restrict__ hT, float* __restrict__ out)
{
    // [row 0..3][buf 0..1][8192 u16] = 128 KB. row: 0=A1,1=A2,2=B1,3=B2.
    __shared__ u16 lds[4 * 2 * 8192];
    __shared__ float smin[8], smax[8];
    __shared__ int hist[4][8];

    const int tid  = threadIdx.x;
    const int lane = tid & 63;
    const int w    = tid >> 6;

    if (tid < 32) hist[tid >> 3][tid & 7] = 0;

    // XCD-bijective swizzle: 528 = 8 * 66 exactly.
    int x = blockIdx.x;
    x = (x & 7) * 66 + (x >> 3);
    // Decode tile -> (ta, tb), ta-major upper triangle (count 32-ta per ta).
    int tt = x, ta = 0, cnt = 32;
    while (tt >= cnt) { tt -= cnt; ++ta; cnt = 32 - ta; }
    const int tb  = ta + tt;
    const int mat = blockIdx.y;

    const int m  = w >> 1;        // matrix 0..3: rows (2ta + (m>>1), 2tb + (m&1))
    const int c  = w & 1;         // 64-col half
    const int l31   = lane & 31;
    const int lhalf = lane >> 5;

    // Staging: thread -> (row = tid>>7, tl = tid&127), copies 8 uint4/slice.
    const int srow = tid >> 7;
    const int tl   = tid & 127;
    const int rsel = (srow < 2) ? (2 * ta + srow) : (2 * tb + (srow - 2));
    const u16* srcp = hT + (size_t)(mat * BS + rsel) * MF + tl * 8;
    const int dstb = srow * 16384 + tl * 8;

    // Fragment bases within lds (u16 units); buf offset added per slice.
    const int aoffW = (m >> 1) * 16384 + lhalf * 1024 + l31 * 8;
    const int boffW = (2 + (m & 1)) * 16384 + lhalf * 1024 + c * 512 + l31 * 8;

    f32x16 acc[4][2];
    #pragma unroll
    for (int ti = 0; ti < 4; ++ti)
        #pragma unroll
        for (int u = 0; u < 2; ++u)
            #pragma unroll
            for (int r = 0; r < 16; ++r) acc[ti][u][r] = 0.0f;

    uint4 sr0, sr1, sr2, sr3, sr4, sr5, sr6, sr7;

    // ---- prologue: slice 0 -> buf0 (latency exposed once per block) ----
    SLOAD(0); SWRITE(0);
    __syncthreads();

    // ---- 4 slices, double-buffered; prefetch s+1 during compute of s ----
    SLOAD(1);
    MFMA_SLICE(0);
    __builtin_amdgcn_sched_barrier(0);
    SWRITE(8192);
    __syncthreads();

    SLOAD(2);
    MFMA_SLICE(8192);
    __builtin_amdgcn_sched_barrier(0);
    SWRITE(0);
    __syncthreads();

    SLOAD(3);
    MFMA_SLICE(0);
    __builtin_amdgcn_sched_barrier(0);
    SWRITE(8192);
    __syncthreads();

    MFMA_SLICE(8192);

    // ---- epilogue: matrix m owned by waves (m,c=0),(m,c=1) ----
    float vmin = acc[0][0][0], vmax = vmin;
    #pragma unroll
    for (int ti = 0; ti < 4; ++ti)
        #pragma unroll
        for (int u = 0; u < 2; ++u)
            #pragma unroll
            for (int r = 0; r < 16; ++r) {
                vmin = fminf(vmin, acc[ti][u][r]);
                vmax = fmaxf(vmax, acc[ti][u][r]);
            }
    #pragma unroll
    for (int off = 1; off < 64; off <<= 1) {
        vmin = fminf(vmin, __shfl_xor(vmin, off, 64));
        vmax = fmaxf(vmax, __shfl_xor(vmax, off, 64));
    }
    if (lane == 0) { smin[w] = vmin; smax[w] = vmax; }
    __syncthreads();
    const float pmn = fminf(smin[m * 2], smin[m * 2 + 1]);
    const float pmx = fmaxf(smax[m * 2], smax[m * 2 + 1]);
    const float denom = (pmx > pmn) ? (pmx - pmn) : 1.0f;
    const float scale = 8.0f / denom;
    const float bias  = -pmn * scale;

    // per-thread packed histogram: 128 values -> 8-bit fields (<=128/bin)
    unsigned w0 = 0, w1 = 0;
    #pragma unroll
    for (int ti = 0; ti < 4; ++ti)
        #pragma unroll
        for (int u = 0; u < 2; ++u)
            #pragma unroll
            for (int r = 0; r < 16; ++r) {
                const float t = fmaf(acc[ti][u][r], scale, bias);
                int k = (int)t;          // t >= -eps; trunc == floor
                k = k > 7 ? 7 : k;
                const unsigned inc = 1u << ((k & 3) * 8);
                if (k < 4) w0 += inc; else w1 += inc;
            }
    unsigned e0 = (w0 & 0xFFu)         | (((w0 >> 8)  & 0xFFu) << 16);
    unsigned e1 = ((w0 >> 16) & 0xFFu) | (((w0 >> 24) & 0xFFu) << 16);
    unsigned e2 = (w1 & 0xFFu)         | (((w1 >> 8)  & 0xFFu) << 16);
    unsigned e3 = ((w1 >> 16) & 0xFFu) | (((w1 >> 24) & 0xFFu) << 16);
    #pragma unroll
    for (int off = 32; off > 0; off >>= 1) {
        e0 += __shfl_down(e0, off, 64);
        e1 += __shfl_down(e1, off, 64);
        e2 += __shfl_down(e2, off, 64);
        e3 += __shfl_down(e3, off, 64);
    }
    if (lane == 0) {
        atomicAdd(&hist[m][0], (int)(e0 & 0xFFFFu)); atomicAdd(&hist[m][1], (int)(e0 >> 16));
        atomicAdd(&hist[m][2], (int)(e1 & 0xFFFFu)); atomicAdd(&hist[m][3], (int)(e1 >> 16));
        atomicAdd(&hist[m][4], (int)(e2 & 0xFFFFu)); atomicAdd(&hist[m][5], (int)(e2 >> 16));
        atomicAdd(&hist[m][6], (int)(e3 & 0xFFFFu)); atomicAdd(&hist[m][7], (int)(e3 >> 16));
    }
    __syncthreads();

    // c==0 wave of each matrix normalizes and writes both symmetric rows.
    // Diagonal-tile transpose twins write identical values (benign).
    if (c == 0 && lane < 8) {
        float ss = 0.0f;
        #pragma unroll
        for (int k = 0; k < 8; ++k) {
            const float cc = (float)hist[m][k];
            ss += cc * cc;
        }
        const float nrm = fmaxf(sqrtf(ss), 1e-12f);
        const float v = (float)hist[m][lane] / nrm;
        const int A = 2 * ta + (m >> 1);
        const int B = 2 * tb + (m & 1);
        out[((size_t)A * BS + B) * 16 + mat * 8 + lane] = v;
        if (A != B)
            out[((size_t)B * BS + A) * 16 + mat * 8 + lane] = v;
    }
}

extern "C" void kernel_launch(void* const* d_in, const int* in_sizes, int n_in,
                              void* d_out, int out_size, void* d_ws, size_t ws_size,
                              hipStream_t stream) {
    const float* m1 = (const float*)d_in[0];
    const float* m2 = (const float*)d_in[1];
    float* out = (float*)d_out;

    // Workspace: granule-major fp16 array, 2*64*128*256 u16 = 8.39 MB.
    u16* hT = (u16*)d_ws;

    convert_f16_kernel<<<dim3(128, 4), 256, 0, stream>>>(m1, m2, hT);
    gram_hist_mfma<<<dim3(NTILE, 2), 512, 0, stream>>>(hT, out);
}

// Round 6
// 115.032 us; speedup vs baseline: 1.1119x; 1.1119x over previous
//
#include <hip/hip_runtime.h>
#include <math.h>

// Problem constants (from reference setup_inputs)
#define BS 64      // batch
#define F  256     // features (K of the Gram matmul)
#define M  128     // columns  (M=N of the Gram matmul)
#define MF (M * F) // u16 elements per matrix in hT
#define NBP 1056   // tiles per mat: sum_a ceil((64-a)/2)

typedef unsigned short u16;
typedef _Float16 f16x8 __attribute__((ext_vector_type(8)));
typedef float    f32x16 __attribute__((ext_vector_type(16)));

// ---------------------------------------------------------------------------
// Pre-pass: fp32 [f][m] -> fp16 GRANULE-MAJOR hT[b][f8][m][8]. (round 6:
// coalesced staging worth 107->58 us; layout verified.)
// ---------------------------------------------------------------------------
__global__ __launch_bounds__(256) void convert_f16_kernel(
    const float* __restrict__ m1, const float* __restrict__ m2,
    u16* __restrict__ hT)
{
    __shared__ float tile[64 * M];   // 32 KB
    const int mat = blockIdx.x >> 6;
    const int b   = blockIdx.x & 63;
    const int f0  = blockIdx.y * 64;
    const float* src = (mat == 0 ? m1 : m2) + (size_t)b * MF + (size_t)f0 * M;
    const int tid = threadIdx.x;

    const float4* g = (const float4*)src;
    float4* s = (float4*)tile;
    #pragma unroll
    for (int i = 0; i < 8; ++i)
        s[tid + i * 256] = g[tid + i * 256];
    __syncthreads();

    const size_t obase = ((size_t)(mat * BS + b) * 32 + (f0 >> 3)) * 1024;
    #pragma unroll
    for (int it = 0; it < 4; ++it) {
        const int idx = it * 256 + tid;
        const int f8l = idx >> 7;
        const int m   = idx & 127;
        u16 hh[8] __attribute__((aligned(16)));
        #pragma unroll
        for (int j = 0; j < 8; ++j) {
            const float x = tile[(f8l * 8 + j) * M + m];  // 2 lanes/bank: free
            const _Float16 h = (_Float16)x;               // RNE
            hh[j] = __builtin_bit_cast(u16, h);
        }
        *(uint4*)&hT[obase + (size_t)idx * 8] = *(const uint4*)hh;
    }
}

// ---------------------------------------------------------------------------
// ROUND 14: L2-RESIDENCY EXPERIMENT. Post-r13 model: the invariant ~7.6 TB/s
// global throughput (405 MB / 53 us in r9) is the L3 service ceiling -- hT
// (8.4 MB) doesn't fit a 4 MiB XCD L2 and round-robin dispatch randomizes
// rows across XCDs, so the ~48x re-read volume is all L2-miss/L3-hit. That
// explains why EVERY schedule variant (barriers r9/r11, prefetch depth r12,
// occupancy r10, byte-cut-at-1-block r13) was neutral-or-worse: same bytes,
// same L3 path. r13 additionally proved 1 block/CU causes phase-aligned
// bursts + drain tail (82 us despite 1.5x fewer bytes).
// FIX: one mat's hT = 64 rows x 64 KiB = EXACTLY 4 MiB = one XCD's L2.
// Flatten the grid to 1D (2112 blocks) and swizzle so XCDs 0-3 process ONLY
// mat 0 and XCDs 4-7 ONLY mat 1: xcd = bid & 7 (HW round-robin), mat =
// xcd >> 2, tile = (xcd & 3) * 264 + (bid >> 3). Bijective; each XCD runs
// 264 blocks, all of one mat, tiles in a contiguous a-band (A-row temporal
// locality too). Working set per XCD == its L2 -> re-reads at L2 speed
// (~37 TB/s chip) instead of L3 (~7.6): memory time 53 -> ~11 us.
// Kernel body is UNCHANGED from the 53.0-us round-9 version (256T, 4 waves,
// wave (pp,c) = 128x64 of pair pp, acc 128 AGPR, 2 blocks/CU, A via LDS
// double-buffer, B direct global->VGPR fragments, reg-prefetch pipeline).
// ---------------------------------------------------------------------------

#define LOADB(DST, CH) {                                      \
    const u16* pbk = pb + (CH) * 4096;                        \
    DST[0][0] = *(const f16x8*)(pbk);                         \
    DST[0][1] = *(const f16x8*)(pbk + 256);                   \
    DST[1][0] = *(const f16x8*)(pbk + 2048);                  \
    DST[1][1] = *(const f16x8*)(pbk + 2048 + 256);            \
}

__global__ __launch_bounds__(256, 2) void gram_hist_mfma(
    const u16* __restrict__ hT, float* __restrict__ out)
{
    __shared__ u16 lds[2 * 4096];   // 16 KB: A tiles only, double-buffered
    __shared__ float smin[4], smax[4];
    __shared__ int hist[2][8];

    const int tid  = threadIdx.x;
    const int lane = tid & 63;
    const int w    = tid >> 6;

    if (tid < 16) hist[tid >> 3][tid & 7] = 0;

    // XCD-pinned mapping: 2112 blocks, 8 XCDs x 264 slots.
    // XCDs 0-3 -> mat 0, XCDs 4-7 -> mat 1; each XCD sees one mat's 4 MiB.
    const int bid  = blockIdx.x;
    const int xcd  = bid & 7;
    const int mat  = xcd >> 2;
    int p = (xcd & 3) * 264 + (bid >> 3);
    // Decode tile p -> (a, pair) with per-a count ceil((64-a)/2).
    int a = 0;
    { int cnt = 32; while (p >= cnt) { p -= cnt; ++a; cnt = (64 - a + 1) >> 1; } }
    const int b1 = a + 2 * p;
    int b2 = b1 + 1;
    const bool b2valid = (b2 <= 63);
    if (!b2valid) b2 = b1;          // duplicate work, writes suppressed

    const int pp = w >> 1;     // which pair (0: b1, 1: b2)
    const int c  = w & 1;      // which 64-col half
    const int l31   = lane & 31;
    const int lhalf = lane >> 5;

    // A staging: one uint4 x 2 per thread per chunk.
    const u16* pa = hT + (size_t)(mat * BS + a) * MF + tid * 8;
    const int d0 = tid * 8;            // A, first 256 granules
    const int d1 = (256 + tid) * 8;    // A, second

    // B fragment per-lane global base (u16 units):
    //   frag(it,kk,u) = pb + it*4096 + kk*2048 + u*256
    const int bsel = pp ? b2 : b1;
    const u16* pb = hT + (size_t)(mat * BS + bsel) * MF
                  + (size_t)(lhalf * 1024 + c * 512 + l31 * 8);

    f32x16 acc[4][2];
    #pragma unroll
    for (int ti = 0; ti < 4; ++ti)
        #pragma unroll
        for (int u = 0; u < 2; ++u)
            #pragma unroll
            for (int r = 0; r < 16; ++r) acc[ti][u][r] = 0.0f;

    uint4 r0, r1;
    f16x8 bA[2][2], bB[2][2];   // double-buffered B fragment sets

    // ---- prologue: A chunk 0 -> LDS, B frags chunk 0 -> bA ----
    r0 = *(const uint4*)(pa);
    r1 = *(const uint4*)(pa + 2048);
    LOADB(bA, 0);
    *(uint4*)&lds[d0] = r0;
    *(uint4*)&lds[d1] = r1;
    __syncthreads();

    #pragma unroll
    for (int itp = 0; itp < 4; ++itp) {
        // even it = 2*itp, cur = buf0: prefetch chunk 2*itp+1 into bB/buf1
        {
            const int nxt = 2 * itp + 1;
            r0 = *(const uint4*)(pa + nxt * 4096);
            r1 = *(const uint4*)(pa + nxt * 4096 + 2048);
            LOADB(bB, nxt);

            const int cur = 0;
            #pragma unroll
            for (int kk = 0; kk < 2; ++kk) {
                const int base = cur + kk * 2048 + lhalf * 1024 + l31 * 8;
                f16x8 af[4];
                #pragma unroll
                for (int t = 0; t < 4; ++t)
                    af[t] = *(const f16x8*)&lds[base + t * 256];
                #pragma unroll
                for (int ti = 0; ti < 4; ++ti) {
                    acc[ti][0] = __builtin_amdgcn_mfma_f32_32x32x16_f16(af[ti], bA[kk][0], acc[ti][0], 0, 0, 0);
                    acc[ti][1] = __builtin_amdgcn_mfma_f32_32x32x16_f16(af[ti], bA[kk][1], acc[ti][1], 0, 0, 0);
                }
            }
            *(uint4*)&lds[4096 + d0] = r0;
            *(uint4*)&lds[4096 + d1] = r1;
            __syncthreads();
        }
        // odd it = 2*itp+1, cur = buf1: prefetch chunk 2*itp+2 into bA/buf0
        {
            if (itp < 3) {
                const int nxt = 2 * itp + 2;
                r0 = *(const uint4*)(pa + nxt * 4096);
                r1 = *(const uint4*)(pa + nxt * 4096 + 2048);
                LOADB(bA, nxt);
            }
            const int cur = 4096;
            #pragma unroll
            for (int kk = 0; kk < 2; ++kk) {
                const int base = cur + kk * 2048 + lhalf * 1024 + l31 * 8;
                f16x8 af[4];
                #pragma unroll
                for (int t = 0; t < 4; ++t)
                    af[t] = *(const f16x8*)&lds[base + t * 256];
                #pragma unroll
                for (int ti = 0; ti < 4; ++ti) {
                    acc[ti][0] = __builtin_amdgcn_mfma_f32_32x32x16_f16(af[ti], bB[kk][0], acc[ti][0], 0, 0, 0);
                    acc[ti][1] = __builtin_amdgcn_mfma_f32_32x32x16_f16(af[ti], bB[kk][1], acc[ti][1], 0, 0, 0);
                }
            }
            if (itp < 3) {
                *(uint4*)&lds[d0] = r0;
                *(uint4*)&lds[d1] = r1;
                __syncthreads();
            }
        }
    }

    // ---- epilogue: pair pp owned by waves (pp,c=0),(pp,c=1) ----
    float vmin = acc[0][0][0], vmax = vmin;
    #pragma unroll
    for (int ti = 0; ti < 4; ++ti)
        #pragma unroll
        for (int u = 0; u < 2; ++u)
            #pragma unroll
            for (int r = 0; r < 16; ++r) {
                vmin = fminf(vmin, acc[ti][u][r]);
                vmax = fmaxf(vmax, acc[ti][u][r]);
            }
    #pragma unroll
    for (int off = 1; off < 64; off <<= 1) {
        vmin = fminf(vmin, __shfl_xor(vmin, off, 64));
        vmax = fmaxf(vmax, __shfl_xor(vmax, off, 64));
    }
    if (lane == 0) { smin[w] = vmin; smax[w] = vmax; }
    __syncthreads();
    const float pmn = fminf(smin[pp * 2], smin[pp * 2 + 1]);
    const float pmx = fmaxf(smax[pp * 2], smax[pp * 2 + 1]);
    const float denom = (pmx > pmn) ? (pmx - pmn) : 1.0f;
    const float scale = 8.0f / denom;
    const float bias  = -pmn * scale;

    // per-thread packed histogram: 128 values -> 8-bit fields (<=128/bin)
    unsigned w0 = 0, w1 = 0;
    #pragma unroll
    for (int ti = 0; ti < 4; ++ti)
        #pragma unroll
        for (int u = 0; u < 2; ++u)
            #pragma unroll
            for (int r = 0; r < 16; ++r) {
                const float t = fmaf(acc[ti][u][r], scale, bias);
                int k = (int)t;          // t >= -eps; trunc == floor
                k = k > 7 ? 7 : k;
                const unsigned inc = 1u << ((k & 3) * 8);
                if (k < 4) w0 += inc; else w1 += inc;
            }
    unsigned e0 = (w0 & 0xFFu)         | (((w0 >> 8)  & 0xFFu) << 16);
    unsigned e1 = ((w0 >> 16) & 0xFFu) | (((w0 >> 24) & 0xFFu) << 16);
    unsigned e2 = (w1 & 0xFFu)         | (((w1 >> 8)  & 0xFFu) << 16);
    unsigned e3 = ((w1 >> 16) & 0xFFu) | (((w1 >> 24) & 0xFFu) << 16);
    #pragma unroll
    for (int off = 32; off > 0; off >>= 1) {
        e0 += __shfl_down(e0, off, 64);
        e1 += __shfl_down(e1, off, 64);
        e2 += __shfl_down(e2, off, 64);
        e3 += __shfl_down(e3, off, 64);
    }
    if (lane == 0) {
        atomicAdd(&hist[pp][0], (int)(e0 & 0xFFFFu)); atomicAdd(&hist[pp][1], (int)(e0 >> 16));
        atomicAdd(&hist[pp][2], (int)(e1 & 0xFFFFu)); atomicAdd(&hist[pp][3], (int)(e1 >> 16));
        atomicAdd(&hist[pp][4], (int)(e2 & 0xFFFFu)); atomicAdd(&hist[pp][5], (int)(e2 >> 16));
        atomicAdd(&hist[pp][6], (int)(e3 & 0xFFFFu)); atomicAdd(&hist[pp][7], (int)(e3 >> 16));
    }
    __syncthreads();

    // one wave per pair normalizes and writes both symmetric rows
    const int B = (pp == 0) ? b1 : b2;
    const bool valid = (pp == 0) || b2valid;
    if (valid && c == 0 && lane < 8) {
        float ss = 0.0f;
        #pragma unroll
        for (int k = 0; k < 8; ++k) {
            const float cc = (float)hist[pp][k];
            ss += cc * cc;
        }
        const float nrm = fmaxf(sqrtf(ss), 1e-12f);
        const float v = (float)hist[pp][lane] / nrm;
        out[((size_t)a * BS + B) * 16 + mat * 8 + lane] = v;
        if (a != B)
            out[((size_t)B * BS + a) * 16 + mat * 8 + lane] = v;
    }
}

extern "C" void kernel_launch(void* const* d_in, const int* in_sizes, int n_in,
                              void* d_out, int out_size, void* d_ws, size_t ws_size,
                              hipStream_t stream) {
    const float* m1 = (const float*)d_in[0];
    const float* m2 = (const float*)d_in[1];
    float* out = (float*)d_out;

    // Workspace: granule-major fp16 array, 2*64*128*256 u16 = 8.39 MB.
    u16* hT = (u16*)d_ws;

    convert_f16_kernel<<<dim3(128, 4), 256, 0, stream>>>(m1, m2, hT);
    gram_hist_mfma<<<2 * NBP, 256, 0, stream>>>(hT, out);
}